// Round 2
// baseline (257.584 us; speedup 1.0000x reference)
//
#include <hip/hip_runtime.h>

#define B_ 4
#define N_ 4096
#define H_ 256
#define L2E 1.44269504088896340736f

typedef _Float16 f16;
typedef f16 f16x8 __attribute__((ext_vector_type(8)));
typedef f16 f16x4 __attribute__((ext_vector_type(4)));
typedef float f32x4 __attribute__((ext_vector_type(4)));

static __device__ __forceinline__ f32x4 mfma16(f16x8 a, f16x8 b, f32x4 c){
  return __builtin_amdgcn_mfma_f32_16x16x32_f16(a, b, c, 0, 0, 0);
}

// async global->LDS, 16B per lane; LDS dest is wave-uniform base + lane*16
static __device__ __forceinline__ void gload16(const void* g, void* l){
  __builtin_amdgcn_global_load_lds(
    (const __attribute__((address_space(1))) unsigned int*)g,
    (__attribute__((address_space(3))) unsigned int*)l, 16, 0, 0);
}

__global__ __launch_bounds__(256, 4) void cvt_f32_f16(
    const float* __restrict__ in, f16* __restrict__ out, int n4){
  int i = blockIdx.x * 256 + threadIdx.x;
  if (i < n4){
    float4 f = ((const float4*)in)[i];
    f16x4 o;
    o[0] = (f16)f.x; o[1] = (f16)f.y; o[2] = (f16)f.z; o[3] = (f16)f.w;
    ((f16x4*)out)[i] = o;
  }
}

// Y[m][o] = sum_h X[m][h]*W[o][h] + bias[o]; M=B*N rows.
// VT==0: Y row-major f16 [M][H].  VT==1: write transposed per batch: Y[b][o][n].
template<int VT>
__global__ __launch_bounds__(256, 4) void proj_kernel(
    const f16* __restrict__ X, const f16* __restrict__ W,
    const float* __restrict__ bias, f16* __restrict__ Y){
  const int tid = threadIdx.x, l = tid & 63, w = tid >> 6;
  const int lr = l & 15, lg = l >> 4;
  const int m0 = blockIdx.x * 64 + w * 16;   // this wave's 16 rows
  const int o0 = blockIdx.y * 64;            // 64 output cols
  f32x4 acc[4] = {{0,0,0,0},{0,0,0,0},{0,0,0,0},{0,0,0,0}};
  const f16* xp = X + (size_t)(m0 + lr) * H_ + lg * 8;
  const f16* wp = W + (size_t)(o0 + lr) * H_ + lg * 8;
  #pragma unroll
  for (int ks = 0; ks < 8; ++ks){
    f16x8 a = *(const f16x8*)(xp + ks * 32);
    #pragma unroll
    for (int ct = 0; ct < 4; ++ct){
      f16x8 b = *(const f16x8*)(wp + (size_t)(ct*16) * H_ + ks * 32);
      acc[ct] = mfma16(a, b, acc[ct]);
    }
  }
  if (VT == 0){
    #pragma unroll
    for (int ct = 0; ct < 4; ++ct){
      float bv = bias[o0 + ct*16 + lr];
      #pragma unroll
      for (int r = 0; r < 4; ++r){
        int row = m0 + lg*4 + r;
        Y[(size_t)row * H_ + o0 + ct*16 + lr] = (f16)(acc[ct][r] + bv);
      }
    }
  } else {
    const int b  = m0 >> 12;                 // 4096 rows per batch, tiles 64-aligned
    const int n0 = (m0 & (N_-1)) + lg*4;     // 4 consecutive n per lane
    #pragma unroll
    for (int ct = 0; ct < 4; ++ct){
      float bv = bias[o0 + ct*16 + lr];
      int o = o0 + ct*16 + lr;
      f16x4 pk;
      pk[0] = (f16)(acc[ct][0] + bv);
      pk[1] = (f16)(acc[ct][1] + bv);
      pk[2] = (f16)(acc[ct][2] + bv);
      pk[3] = (f16)(acc[ct][3] + bv);
      *(f16x4*)(Y + ((size_t)(b * H_ + o)) * N_ + n0) = pk;
    }
  }
}

// Flash attention: 1 block = (batch b, 64 q-rows); 4 waves x 16 q-rows.
// K tile [64][256] and Vt tile [256][64] staged to LDS (double-buffered) via
// global_load_lds with source-pre-swizzled addresses; reads XOR-swizzled.
__global__ __launch_bounds__(256, 1) void flash_kernel(
    const f16* __restrict__ Q, const f16* __restrict__ K,
    const f16* __restrict__ Vt, float* __restrict__ O){
  __shared__ f16 Kl[2][64*256];   // 32KB x2, row = 512B = 32 chunks
  __shared__ f16 Vl[2][256*64];   // 32KB x2, row = 128B = 8 chunks
  __shared__ f16 Pl[4][16*72];    // per-wave P, padded stride 72
  const int tid = threadIdx.x, l = tid & 63, w = tid >> 6;
  const int lr = l & 15, lg = l >> 4;
  const int b = blockIdx.x >> 6, qt = blockIdx.x & 63;
  const int q0 = qt * 64;
  const f16* Kg = K  + (size_t)b * N_ * H_;
  const f16* Vg = Vt + (size_t)b * H_ * N_;

  // hoist Q fragments (16 rows x 256 k-dim = 8 A-frags)
  f16x8 qf[8];
  {
    const f16* qp = Q + ((size_t)b * N_ + q0 + w*16 + lr) * H_ + lg*8;
    #pragma unroll
    for (int ks = 0; ks < 8; ++ks) qf[ks] = *(const f16x8*)(qp + ks*32);
  }

  f32x4 oacc[16];
  #pragma unroll
  for (int ft = 0; ft < 16; ++ft) oacc[ft] = {0.f,0.f,0.f,0.f};
  float m_run[4], l_run[4];
  #pragma unroll
  for (int r = 0; r < 4; ++r){ m_run[r] = -3.0e38f; l_run[r] = 0.f; }

  auto stage = [&](int buf, int t){
    const int kv0 = t * 64;
    #pragma unroll
    for (int i = 0; i < 8; ++i){          // K: 2048 16B chunks
      int c = i*256 + tid;
      int r = c >> 5, x = c & 31;         // row, chunk-in-row
      gload16(Kg + (size_t)(kv0 + r)*H_ + ((x ^ (r & 7)) << 3),
              &Kl[buf][(i*256 + w*64) * 8]);
    }
    #pragma unroll
    for (int i = 0; i < 8; ++i){          // Vt: 2048 16B chunks
      int c = i*256 + tid;
      int f = c >> 3, x = c & 7;
      gload16(Vg + (size_t)f*N_ + kv0 + ((x ^ (f & 7)) << 3),
              &Vl[buf][(i*256 + w*64) * 8]);
    }
  };

  stage(0, 0);
  __syncthreads();

  for (int t = 0; t < 64; ++t){
    const int cur = t & 1;
    if (t + 1 < 64) stage(cur ^ 1, t + 1);   // prefetch next tile (m97 overlap)

    // ---- S = Q K^T : 16q x 64kv
    f32x4 s[4];
    #pragma unroll
    for (int ct = 0; ct < 4; ++ct) s[ct] = {0.f,0.f,0.f,0.f};
    const char* Kb = (const char*)Kl[cur];
    #pragma unroll
    for (int ks = 0; ks < 8; ++ks){
      #pragma unroll
      for (int ct = 0; ct < 4; ++ct){
        const int n  = ct*16 + lr;          // kv row
        const int cw = ks*4 + lg;           // wanted 16B chunk
        f16x8 bf = *(const f16x8*)(Kb + n*512 + ((cw ^ (n & 7)) << 4));
        s[ct] = mfma16(qf[ks], bf, s[ct]);
      }
    }

    // ---- online softmax (rows = lg*4+r, cols spread over 16 lanes)
    float mx[4];
    #pragma unroll
    for (int r = 0; r < 4; ++r)
      mx[r] = fmaxf(fmaxf(s[0][r], s[1][r]), fmaxf(s[2][r], s[3][r]));
    #pragma unroll
    for (int d = 1; d < 16; d <<= 1)
      #pragma unroll
      for (int r = 0; r < 4; ++r) mx[r] = fmaxf(mx[r], __shfl_xor(mx[r], d));
    float al[4];
    #pragma unroll
    for (int r = 0; r < 4; ++r){
      float mn = fmaxf(m_run[r], mx[r]);
      al[r] = __builtin_amdgcn_exp2f((m_run[r] - mn) * L2E);
      m_run[r] = mn;
    }
    float ps[4] = {0.f,0.f,0.f,0.f};
    #pragma unroll
    for (int ct = 0; ct < 4; ++ct)
      #pragma unroll
      for (int r = 0; r < 4; ++r){
        float p = __builtin_amdgcn_exp2f((s[ct][r] - m_run[r]) * L2E);
        s[ct][r] = p;
        ps[r] += p;
      }
    #pragma unroll
    for (int d = 1; d < 16; d <<= 1)
      #pragma unroll
      for (int r = 0; r < 4; ++r) ps[r] += __shfl_xor(ps[r], d);
    #pragma unroll
    for (int r = 0; r < 4; ++r) l_run[r] = l_run[r] * al[r] + ps[r];
    #pragma unroll
    for (int ft = 0; ft < 16; ++ft)
      #pragma unroll
      for (int r = 0; r < 4; ++r) oacc[ft][r] *= al[r];

    // ---- P (C-layout) -> per-wave LDS -> A-frag layout
    f16* Pw = Pl[w];
    #pragma unroll
    for (int ct = 0; ct < 4; ++ct)
      #pragma unroll
      for (int r = 0; r < 4; ++r)
        Pw[(lg*4 + r)*72 + ct*16 + lr] = (f16)s[ct][r];

    // ---- O += P V   (B-frag = contiguous read from Vt row = feature)
    const char* Vb = (const char*)Vl[cur];
    const char* Pb = (const char*)Pw;
    #pragma unroll
    for (int ks2 = 0; ks2 < 2; ++ks2){
      f16x8 af = *(const f16x8*)(Pb + lr*144 + ks2*64 + lg*16);
      #pragma unroll
      for (int ft = 0; ft < 16; ++ft){
        const int f  = ft*16 + lr;
        const int cw = ks2*4 + lg;
        f16x8 bf = *(const f16x8*)(Vb + f*128 + ((cw ^ (f & 7)) << 4));
        oacc[ft] = mfma16(af, bf, oacc[ft]);
      }
    }
    __syncthreads();   // drains vmcnt(0): next-tile stage complete
  }

  float inv[4];
  #pragma unroll
  for (int r = 0; r < 4; ++r) inv[r] = 1.0f / l_run[r];
  float* Ob = O + ((size_t)b * N_ + q0 + w*16) * H_;
  #pragma unroll
  for (int ft = 0; ft < 16; ++ft)
    #pragma unroll
    for (int r = 0; r < 4; ++r)
      Ob[(size_t)(lg*4 + r) * H_ + ft*16 + lr] = oacc[ft][r] * inv[r];
}

extern "C" void kernel_launch(void* const* d_in, const int* in_sizes, int n_in,
                              void* d_out, int out_size, void* d_ws, size_t ws_size,
                              hipStream_t stream) {
  const float* x  = (const float*)d_in[0];
  const float* Wq = (const float*)d_in[1];
  const float* bq = (const float*)d_in[2];
  const float* Wk = (const float*)d_in[3];
  const float* bk = (const float*)d_in[4];
  const float* Wv = (const float*)d_in[5];
  const float* bv = (const float*)d_in[6];
  float* out = (float*)d_out;

  // workspace layout (needs ~34 MB)
  char* ws = (char*)d_ws;
  const size_t SZ = (size_t)B_ * N_ * H_ * 2;          // 8,388,608 B
  f16* xb  = (f16*)(ws);
  f16* qb  = (f16*)(ws + SZ);
  f16* kb  = (f16*)(ws + 2*SZ);
  f16* vt  = (f16*)(ws + 3*SZ);  // [B][H][N]
  f16* wqb = (f16*)(ws + 4*SZ);
  f16* wkb = wqb + H_*H_;
  f16* wvb = wkb + H_*H_;

  cvt_f32_f16<<<(B_*N_*H_/4 + 255)/256, 256, 0, stream>>>(x,  xb,  B_*N_*H_/4);
  cvt_f32_f16<<<(H_*H_/4   + 255)/256, 256, 0, stream>>>(Wq, wqb, H_*H_/4);
  cvt_f32_f16<<<(H_*H_/4   + 255)/256, 256, 0, stream>>>(Wk, wkb, H_*H_/4);
  cvt_f32_f16<<<(H_*H_/4   + 255)/256, 256, 0, stream>>>(Wv, wvb, H_*H_/4);

  dim3 pgrid(B_*N_/64, H_/64);
  proj_kernel<0><<<pgrid, 256, 0, stream>>>(xb, wqb, bq, qb);
  proj_kernel<0><<<pgrid, 256, 0, stream>>>(xb, wkb, bk, kb);
  proj_kernel<1><<<pgrid, 256, 0, stream>>>(xb, wvb, bv, vt);

  flash_kernel<<<B_*(N_/64), 256, 0, stream>>>(qb, kb, vt, out);
}